// Round 6
// baseline (241.565 us; speedup 1.0000x reference)
//
#include <hip/hip_runtime.h>
#include <hip/hip_bf16.h>
#include <cstdint>

#define BATCH 4
#define S_LEN 2048
#define D_DIM 1024

typedef __attribute__((ext_vector_type(4))) float f32x4_t;
typedef __attribute__((ext_vector_type(8))) __bf16 bf16x8_t;

__device__ __forceinline__ ushort f32_to_bf16(float f) {
    uint32_t u = __float_as_uint(f);
    uint32_t r = (u + 0x7FFFu + ((u >> 16) & 1u)) >> 16;
    return (ushort)r;
}

// ---------------- fp32 -> bf16 convert, 3 tensors in one launch ----------------
__global__ __launch_bounds__(256)
void cvt3_kernel(const float* __restrict__ a, const float* __restrict__ b,
                 const float* __restrict__ c, ushort* __restrict__ out, int n4) {
    int z = blockIdx.y;
    const float* src = (z == 0) ? a : ((z == 1) ? b : c);
    ushort* dst = out + (size_t)z * n4 * 4;
    int idx = blockIdx.x * blockDim.x + threadIdx.x;
    int stride = gridDim.x * blockDim.x;
    const float4* in4 = (const float4*)src;
    ushort4* out4 = (ushort4*)dst;
    for (int i = idx; i < n4; i += stride) {
        float4 v = in4[i];
        ushort4 o;
        o.x = f32_to_bf16(v.x);
        o.y = f32_to_bf16(v.y);
        o.z = f32_to_bf16(v.z);
        o.w = f32_to_bf16(v.w);
        out4[i] = o;
    }
}

// ---------------- fp32 [rows][cols] -> bf16 [cols][rows] ----------------
__global__ __launch_bounds__(256)
void transpose_cvt_kernel(const float* __restrict__ in, ushort* __restrict__ out,
                          int rows, int cols) {
    __shared__ ushort tile[64][66];
    int r0 = blockIdx.y * 64, c0 = blockIdx.x * 64;
    int t = threadIdx.x;
    int cr = t & 63;
    int cc = t >> 6;
    #pragma unroll
    for (int i = 0; i < 16; ++i) {
        int r = cc * 16 + i;
        tile[r][cr] = f32_to_bf16(in[(size_t)(r0 + r) * cols + (c0 + cr)]);
    }
    __syncthreads();
    #pragma unroll
    for (int i = 0; i < 16; ++i) {
        int c = cc * 16 + i;
        out[(size_t)(c0 + c) * rows + (r0 + cr)] = tile[cr][c];
    }
}

// ---------------- bf16 strided [rows][cols] -> bf16 [cols][rows], batched ----------------
__global__ __launch_bounds__(256)
void transpose_bf16_kernel(const ushort* __restrict__ in, ushort* __restrict__ out,
                           int rows, int cols, int lda, long strideA, long strideB) {
    __shared__ ushort tile[64][66];
    const ushort* src = in + (size_t)blockIdx.z * strideA;
    ushort* dst = out + (size_t)blockIdx.z * strideB;
    int r0 = blockIdx.y * 64, c0 = blockIdx.x * 64;
    int t = threadIdx.x;
    int cr = t & 63;
    int cc = t >> 6;
    #pragma unroll
    for (int i = 0; i < 16; ++i) {
        int r = cc * 16 + i;
        tile[r][cr] = src[(size_t)(r0 + r) * lda + (c0 + cr)];
    }
    __syncthreads();
    #pragma unroll
    for (int i = 0; i < 16; ++i) {
        int c = cc * 16 + i;
        dst[(size_t)(c0 + c) * rows + (r0 + cr)] = tile[cr][c];
    }
}

// ---------------- bias concat ----------------
__global__ __launch_bounds__(256)
void bias_concat_kernel(const float* __restrict__ bq, const float* __restrict__ bk,
                        const float* __restrict__ bv, float* __restrict__ out) {
    int i = blockIdx.x * blockDim.x + threadIdx.x;
    if (i < D_DIM) out[i] = bq[i];
    else if (i < 2 * D_DIM) out[i] = bk[i - D_DIM];
    else if (i < 3 * D_DIM) out[i] = bv[i - 2 * D_DIM];
}

// =====================================================================
// Software-pipelined GEMM: 256x128 tile, BK=64, 8 waves (4x2, wave 64x64),
// 3 LDS slots, reads one K-tile ahead (reg double-set), 2 barriers/K-tile,
// counted vmcnt(6)/lgkmcnt(8). C = A(MxK) * Bt(NxK)^T.
// =====================================================================
enum { MODE_PROJ = 0, MODE_LOGITS = 1, MODE_OUT = 2 };

#define LGKM(N) do { asm volatile("s_waitcnt lgkmcnt(" #N ")" ::: "memory"); \
    __builtin_amdgcn_sched_barrier(0); } while (0)
#define GATE(N) do { asm volatile("s_waitcnt vmcnt(" #N ")" ::: "memory"); \
    __builtin_amdgcn_sched_barrier(0); } while (0)

#define GLOAD(dst, src) __builtin_amdgcn_global_load_lds( \
    (const __attribute__((address_space(1))) uint32_t*)(src), \
    (__attribute__((address_space(3))) uint32_t*)(dst), 16, 0, 0)

// bijective XCD swizzle over (x,y) grid (requires nwg%8==0)
__device__ __forceinline__ void xcd_swizzle(int& bc, int& br) {
    int gx = gridDim.x;
    int nwg = gx * gridDim.y;
    int orig = blockIdx.y * gx + blockIdx.x;
    int xcd = orig & 7, idx = orig >> 3;
    int wgid = xcd * (nwg >> 3) + idx;
    bc = wgid % gx;
    br = wgid / gx;
}

template<int MODE>
__global__ __launch_bounds__(512, 2)
void gemm_pipe_kernel(const ushort* __restrict__ A, const ushort* __restrict__ Bt,
                      const float* __restrict__ bias, void* __restrict__ Cout,
                      int K, int lda, int ldb, int ldc,
                      long strideA, long strideB, long strideC, float scale) {
    __shared__ ushort As[3][256 * 64];   // 3 x 32 KB
    __shared__ ushort Bs[3][128 * 64];   // 3 x 16 KB
    int bc, br;
    xcd_swizzle(bc, br);
    int bz = blockIdx.z;
    if (MODE == MODE_LOGITS && bc > 2 * br + 1) return;  // fully-masked causal block
    const ushort* Ab = (MODE == MODE_PROJ) ? A + (size_t)(bc >> 3) * strideA
                                           : A + (size_t)bz * strideA;
    const ushort* Bb = Bt + (size_t)bz * strideB;
    int brow = br * 256, bcol = bc * 128;
    int t = threadIdx.x, lane = t & 63, wid = t >> 6;
    int wr = wid >> 1, wc = wid & 1;          // 4x2 waves, wave tile 64x64
    int nkt = K / 64;
    if (MODE == MODE_OUT) nkt = min(nkt, (brow + 256) / 64);  // even, >= 4

    // ---- per-thread staging sources (linear LDS dest, inverse-swizzled src) ----
    const ushort* aSrc[4];
    const ushort* bSrc[2];
    int oA[4], oB[2];
    #pragma unroll
    for (int j = 0; j < 4; ++j) {
        int o = (j * 512 + t) * 16;
        int row = o >> 7;
        int col = (o & 127) ^ ((row & 7) << 4);
        oA[j] = o >> 1;
        aSrc[j] = Ab + (size_t)(brow + row) * lda + (col >> 1);
    }
    #pragma unroll
    for (int j = 0; j < 2; ++j) {
        int o = (j * 512 + t) * 16;
        int row = o >> 7;
        int col = (o & 127) ^ ((row & 7) << 4);
        oB[j] = o >> 1;
        bSrc[j] = Bb + (size_t)(bcol + row) * ldb + (col >> 1);
    }
    auto stage = [&](int tk, int slot) {   // 6 gloads (A 32 KB + B 16 KB)
        ushort* dA = &As[slot][0];
        ushort* dB = &Bs[slot][0];
        #pragma unroll
        for (int j = 0; j < 4; ++j) GLOAD(dA + oA[j], aSrc[j] + tk * 64);
        #pragma unroll
        for (int j = 0; j < 2; ++j) GLOAD(dB + oB[j], bSrc[j] + tk * 64);
    };

    // ---- per-lane fragment read offsets (swizzled) ----
    int rdA[4][2], rdB[4][2];
    #pragma unroll
    for (int m = 0; m < 4; ++m) {
        int ra = wr * 64 + m * 16 + (lane & 15);
        #pragma unroll
        for (int ks = 0; ks < 2; ++ks) {
            int cb = ks * 64 + ((lane >> 4) * 16);
            rdA[m][ks] = ra * 128 + (cb ^ ((ra & 7) << 4));
        }
    }
    #pragma unroll
    for (int n = 0; n < 4; ++n) {
        int rb = wc * 64 + n * 16 + (lane & 15);
        #pragma unroll
        for (int ks = 0; ks < 2; ++ks) {
            int cb = ks * 64 + ((lane >> 4) * 16);
            rdB[n][ks] = rb * 128 + (cb ^ ((rb & 7) << 4));
        }
    }

    f32x4_t acc[4][4];
    #pragma unroll
    for (int m = 0; m < 4; ++m)
        #pragma unroll
        for (int n = 0; n < 4; ++n)
            acc[m][n] = (f32x4_t){0.f, 0.f, 0.f, 0.f};

    bf16x8_t aE0[4], aE1[4], bE0[4], bE1[4];   // even-tile fragments
    bf16x8_t aO0[4], aO1[4], bO0[4], bO1[4];   // odd-tile fragments

#define MF16(AV, BV)                                                           \
    do { __builtin_amdgcn_s_setprio(1);                                        \
        _Pragma("unroll") for (int m = 0; m < 4; ++m)                          \
        _Pragma("unroll") for (int n = 0; n < 4; ++n)                          \
            acc[m][n] = __builtin_amdgcn_mfma_f32_16x16x32_bf16(               \
                AV[m], BV[n], acc[m][n], 0, 0, 0);                             \
        __builtin_amdgcn_s_setprio(0); } while (0)

    // One K-tile: cur fragments already loaded; prefetch next tile's fragments.
#define TILE_BODY(X, CA0, CA1, CB0, CB1, NA0, NA1, NB0, NB1)                   \
    do {                                                                       \
        int x_ = (X);                                                          \
        __builtin_amdgcn_s_barrier();            /* readers of slot(x-1) done */ \
        if (x_ + 2 < nkt) stage(x_ + 2, (x_ + 2) % 3);                         \
        if (x_ + 1 < nkt) { if (x_ + 2 < nkt) { GATE(6); } else { GATE(0); } } \
        __builtin_amdgcn_s_barrier();            /* slot(x+1) staged for all */ \
        {                                                                      \
            const char* nA = (const char*)&As[(x_ + 1) % 3][0];                \
            const char* nB = (const char*)&Bs[(x_ + 1) % 3][0];                \
            if (x_ + 1 < nkt) {                                                \
                _Pragma("unroll") for (int n = 0; n < 4; ++n)                  \
                    NB0[n] = *(const bf16x8_t*)(nB + rdB[n][0]);               \
                _Pragma("unroll") for (int m = 0; m < 4; ++m)                  \
                    NA0[m] = *(const bf16x8_t*)(nA + rdA[m][0]);               \
                LGKM(8);                 /* all reads(x) done; 8 new in flight */ \
            } else { LGKM(0); }                                                \
            MF16(CA0, CB0);                                                    \
            if (x_ + 1 < nkt) {                                                \
                _Pragma("unroll") for (int n = 0; n < 4; ++n)                  \
                    NB1[n] = *(const bf16x8_t*)(nB + rdB[n][1]);               \
                _Pragma("unroll") for (int m = 0; m < 4; ++m)                  \
                    NA1[m] = *(const bf16x8_t*)(nA + rdA[m][1]);               \
            }                                                                  \
            MF16(CA1, CB1);                                                    \
        }                                                                      \
    } while (0)

    // ---- prologue: stage tiles 0,1; load tile-0 fragments ----
    stage(0, 0);
    stage(1, 1);
    GATE(6);                                  // own part of tile 0 landed
    __builtin_amdgcn_s_barrier();             // everyone's tile 0 landed
    {
        const char* pA = (const char*)&As[0][0];
        const char* pB = (const char*)&Bs[0][0];
        #pragma unroll
        for (int n = 0; n < 4; ++n) bE0[n] = *(const bf16x8_t*)(pB + rdB[n][0]);
        #pragma unroll
        for (int m = 0; m < 4; ++m) aE0[m] = *(const bf16x8_t*)(pA + rdA[m][0]);
        #pragma unroll
        for (int n = 0; n < 4; ++n) bE1[n] = *(const bf16x8_t*)(pB + rdB[n][1]);
        #pragma unroll
        for (int m = 0; m < 4; ++m) aE1[m] = *(const bf16x8_t*)(pA + rdA[m][1]);
    }

    int nhalf = nkt >> 1;
    for (int it = 0; it < nhalf; ++it) {
        int x = 2 * it;
        TILE_BODY(x,     aE0, aE1, bE0, bE1, aO0, aO1, bO0, bO1);
        TILE_BODY(x + 1, aO0, aO1, bO0, bO1, aE0, aE1, bE0, bE1);
    }
#undef TILE_BODY
#undef MF16

    // ---- epilogue: C/D layout col = lane&15, row = (lane>>4)*4 + j ----
    int crow0 = brow + wr * 64 + ((lane >> 4) * 4);
    int ccol0 = bcol + wc * 64 + (lane & 15);
    if (MODE == MODE_PROJ) {
        ushort* C = (ushort*)Cout;
        #pragma unroll
        for (int mf = 0; mf < 4; ++mf) {
            #pragma unroll
            for (int nf = 0; nf < 4; ++nf) {
                int col = ccol0 + nf * 16;
                float bv = bias[col];
                #pragma unroll
                for (int j = 0; j < 4; ++j) {
                    int rowg = crow0 + mf * 16 + j;
                    C[(size_t)rowg * ldc + col] = f32_to_bf16(acc[mf][nf][j] + bv);
                }
            }
        }
    } else {
        float* C = (float*)Cout + (size_t)bz * strideC;
        #pragma unroll
        for (int mf = 0; mf < 4; ++mf)
            #pragma unroll
            for (int nf = 0; nf < 4; ++nf) {
                int col = ccol0 + nf * 16;
                #pragma unroll
                for (int j = 0; j < 4; ++j) {
                    int rowg = crow0 + mf * 16 + j;
                    C[(size_t)rowg * ldc + col] = acc[mf][nf][j] * scale;
                }
            }
    }
}

// ---------------- causal row softmax (in-place fp32, plus bf16 copy) ----------------
__global__ __launch_bounds__(256)
void softmax_causal_kernel(float* __restrict__ attn, ushort* __restrict__ attn_bf) {
    int rowid = blockIdx.x;
    int i = rowid & (S_LEN - 1);
    float* lrow = attn + (size_t)rowid * S_LEN;
    ushort* brw = attn_bf + (size_t)rowid * S_LEN;
    int t = threadIdx.x;
    int nvalid = i + 1;

    float vals[8];
    float lmax = -1e30f;
    #pragma unroll
    for (int it = 0; it < 8; ++it) {
        int j = it * 256 + t;
        float v = (j < nvalid) ? lrow[j] : -1e30f;
        vals[it] = v;
        lmax = fmaxf(lmax, v);
    }
    #pragma unroll
    for (int off = 32; off > 0; off >>= 1)
        lmax = fmaxf(lmax, __shfl_xor(lmax, off));

    __shared__ float redm[4];
    __shared__ float reds[4];
    int wave = t >> 6, lane = t & 63;
    if (lane == 0) redm[wave] = lmax;
    __syncthreads();
    float m = fmaxf(fmaxf(redm[0], redm[1]), fmaxf(redm[2], redm[3]));

    float lsum = 0.f;
    #pragma unroll
    for (int it = 0; it < 8; ++it) {
        int j = it * 256 + t;
        float e = (j < nvalid) ? __expf(vals[it] - m) : 0.f;
        vals[it] = e;
        lsum += e;
    }
    #pragma unroll
    for (int off = 32; off > 0; off >>= 1)
        lsum += __shfl_xor(lsum, off);
    if (lane == 0) reds[wave] = lsum;
    __syncthreads();
    float denom = reds[0] + reds[1] + reds[2] + reds[3];
    float inv = 1.f / denom;

    #pragma unroll
    for (int it = 0; it < 8; ++it) {
        int j = it * 256 + t;
        float p = vals[it] * inv;
        lrow[j] = p;
        brw[j] = f32_to_bf16(p);
    }
}

extern "C" void kernel_launch(void* const* d_in, const int* in_sizes, int n_in,
                              void* d_out, int out_size, void* d_ws, size_t ws_size,
                              hipStream_t stream) {
    const float* v  = (const float*)d_in[0];
    const float* k  = (const float*)d_in[1];
    const float* q  = (const float*)d_in[2];
    // d_in[3] = mask, unused (causality applied by index)
    const float* Wq = (const float*)d_in[4];
    const float* bq = (const float*)d_in[5];
    const float* Wk = (const float*)d_in[6];
    const float* bk = (const float*)d_in[7];
    const float* Wv = (const float*)d_in[8];
    const float* bv = (const float*)d_in[9];

    float* out  = (float*)d_out;                                        // [B,S,D]
    float* attn = (float*)d_out + (size_t)BATCH * S_LEN * D_DIM;        // [B,S,S]

    char* ws = (char*)d_ws;
    const size_t NTOK = (size_t)BATCH * S_LEN;                // 8192
    const size_t XSZ  = NTOK * D_DIM * sizeof(ushort);        // 16 MiB
    ushort* xqkv  = (ushort*)(ws);                            // [3][8192][1024] bf16
    ushort* qkvp  = (ushort*)(ws + 3 * XSZ);                  // [8192][3072] bf16
    ushort* WT    = (ushort*)(ws + 6 * XSZ);                  // [3072][1024] bf16
    float*  bias3 = (float*)(ws + 6 * XSZ + 3 * (size_t)D_DIM * D_DIM * sizeof(ushort));
    // aliases over xqkv (dead after projection GEMM):
    ushort* vpT     = (ushort*)(ws);            // [B][1024][2048] bf16
    ushort* attn_bf = (ushort*)(ws + XSZ);      // [B][2048][2048] bf16

    const int n4 = (int)(NTOK * D_DIM / 4);
    cvt3_kernel<<<dim3(1024, 3), dim3(256), 0, stream>>>(q, k, v, xqkv, n4);

    transpose_cvt_kernel<<<dim3(16, 16), dim3(256), 0, stream>>>(Wq, WT, D_DIM, D_DIM);
    transpose_cvt_kernel<<<dim3(16, 16), dim3(256), 0, stream>>>(Wk, WT + (size_t)D_DIM * D_DIM, D_DIM, D_DIM);
    transpose_cvt_kernel<<<dim3(16, 16), dim3(256), 0, stream>>>(Wv, WT + 2 * (size_t)D_DIM * D_DIM, D_DIM, D_DIM);
    bias_concat_kernel<<<dim3(12), dim3(256), 0, stream>>>(bq, bk, bv, bias3);

    // merged projections: M = 8192, N = 3072 (q|k|v), K = 1024 — grid 768 = 3.0 rounds
    gemm_pipe_kernel<MODE_PROJ><<<dim3(24, 32, 1), dim3(512), 0, stream>>>(
        xqkv, WT, bias3, qkvp, D_DIM, D_DIM, D_DIM, 3 * D_DIM,
        (long)NTOK * D_DIM, 0, 0, 1.f);

    // vp (cols 2048..3071 of qkvp) -> vpT [B,D,S]
    transpose_bf16_kernel<<<dim3(D_DIM / 64, S_LEN / 64, BATCH), dim3(256), 0, stream>>>(
        qkvp + 2 * D_DIM, vpT, S_LEN, D_DIM, 3 * D_DIM,
        (long)S_LEN * 3 * D_DIM, (long)D_DIM * S_LEN);

    // logits = qp @ kp^T / 32, causal blocks only, fp32 into attn region of d_out
    gemm_pipe_kernel<MODE_LOGITS><<<dim3(16, 8, BATCH), dim3(512), 0, stream>>>(
        qkvp, qkvp + D_DIM, nullptr, attn, D_DIM, 3 * D_DIM, 3 * D_DIM, S_LEN,
        (long)S_LEN * 3 * D_DIM, (long)S_LEN * 3 * D_DIM, (long)S_LEN * S_LEN, 0.03125f);

    // softmax rows (fp32 in-place in d_out; bf16 copy for PV)
    softmax_causal_kernel<<<dim3((int)NTOK), dim3(256), 0, stream>>>(attn, attn_bf);

    // out = attn_bf @ vp (via vpT), causal K-limit
    gemm_pipe_kernel<MODE_OUT><<<dim3(8, 8, BATCH), dim3(512), 0, stream>>>(
        attn_bf, vpT, nullptr, out, S_LEN, S_LEN, S_LEN, D_DIM,
        (long)S_LEN * S_LEN, (long)D_DIM * S_LEN, (long)S_LEN * D_DIM, 1.f);
}

// Round 7
// 219.998 us; speedup vs baseline: 1.0980x; 1.0980x over previous
//
#include <hip/hip_runtime.h>
#include <hip/hip_bf16.h>
#include <cstdint>

#define BATCH 4
#define S_LEN 2048
#define D_DIM 1024

typedef __attribute__((ext_vector_type(4))) float f32x4_t;
typedef __attribute__((ext_vector_type(8))) __bf16 bf16x8_t;

__device__ __forceinline__ ushort f32_to_bf16(float f) {
    uint32_t u = __float_as_uint(f);
    uint32_t r = (u + 0x7FFFu + ((u >> 16) & 1u)) >> 16;
    return (ushort)r;
}

// ---------------- fp32 -> bf16 convert, 3 tensors in one launch ----------------
__global__ __launch_bounds__(256)
void cvt3_kernel(const float* __restrict__ a, const float* __restrict__ b,
                 const float* __restrict__ c, ushort* __restrict__ out, int n4) {
    int z = blockIdx.y;
    const float* src = (z == 0) ? a : ((z == 1) ? b : c);
    ushort* dst = out + (size_t)z * n4 * 4;
    int idx = blockIdx.x * blockDim.x + threadIdx.x;
    int stride = gridDim.x * blockDim.x;
    const float4* in4 = (const float4*)src;
    ushort4* out4 = (ushort4*)dst;
    for (int i = idx; i < n4; i += stride) {
        float4 v = in4[i];
        ushort4 o;
        o.x = f32_to_bf16(v.x);
        o.y = f32_to_bf16(v.y);
        o.z = f32_to_bf16(v.z);
        o.w = f32_to_bf16(v.w);
        out4[i] = o;
    }
}

// ---------------- fp32 [rows][cols] -> bf16 [cols][rows] ----------------
__global__ __launch_bounds__(256)
void transpose_cvt_kernel(const float* __restrict__ in, ushort* __restrict__ out,
                          int rows, int cols) {
    __shared__ ushort tile[64][66];
    int r0 = blockIdx.y * 64, c0 = blockIdx.x * 64;
    int t = threadIdx.x;
    int cr = t & 63;
    int cc = t >> 6;
    #pragma unroll
    for (int i = 0; i < 16; ++i) {
        int r = cc * 16 + i;
        tile[r][cr] = f32_to_bf16(in[(size_t)(r0 + r) * cols + (c0 + cr)]);
    }
    __syncthreads();
    #pragma unroll
    for (int i = 0; i < 16; ++i) {
        int c = cc * 16 + i;
        out[(size_t)(c0 + c) * rows + (r0 + cr)] = tile[cr][c];
    }
}

// ---------------- bias concat ----------------
__global__ __launch_bounds__(256)
void bias_concat_kernel(const float* __restrict__ bq, const float* __restrict__ bk,
                        const float* __restrict__ bv, float* __restrict__ out) {
    int i = blockIdx.x * blockDim.x + threadIdx.x;
    if (i < D_DIM) out[i] = bq[i];
    else if (i < 2 * D_DIM) out[i] = bk[i - D_DIM];
    else if (i < 3 * D_DIM) out[i] = bv[i - 2 * D_DIM];
}

enum { MODE_PROJ = 0, MODE_LOGITS = 1, MODE_OUT = 2 };

#define PRE_BAR() do { __builtin_amdgcn_s_barrier(); \
    asm volatile("s_waitcnt lgkmcnt(0)" ::: "memory"); \
    __builtin_amdgcn_sched_barrier(0); } while (0)
#define POST_BAR() do { __builtin_amdgcn_sched_barrier(0); \
    __builtin_amdgcn_s_barrier(); } while (0)
#define GATE(N) do { asm volatile("s_waitcnt vmcnt(" #N ")" ::: "memory"); \
    __builtin_amdgcn_sched_barrier(0); } while (0)

#define GLOAD(dst, src) __builtin_amdgcn_global_load_lds( \
    (const __attribute__((address_space(1))) uint32_t*)(src), \
    (__attribute__((address_space(3))) uint32_t*)(dst), 16, 0, 0)

// bijective XCD swizzle over (x,y) grid (requires nwg%8==0)
__device__ __forceinline__ void xcd_swizzle(int& bc, int& br) {
    int gx = gridDim.x;
    int nwg = gx * gridDim.y;
    int orig = blockIdx.y * gx + blockIdx.x;
    int xcd = orig & 7, idx = orig >> 3;
    int wgid = xcd * (nwg >> 3) + idx;
    bc = wgid % gx;
    br = wgid / gx;
}

// =====================================================================
// m201-geometry GEMM: 256x256 tile, BK=64, 8 waves (2x4), wave tile 128x64,
// 2 LDS slots (128 KB), 4 quadrant-phases per K-tile, counted vmcnt gates.
// C = A(MxK) * Bt(NxK)^T.  PROJ and LOGITS.
// Wave col layout: col = nh*128 + wc*32 + n*16  (aligns B-halves to gloads).
// =====================================================================
template<int MODE>
__global__ __launch_bounds__(512, 2)
void gemm_q_kernel(const ushort* __restrict__ A, const ushort* __restrict__ Bt,
                   const float* __restrict__ bias, void* __restrict__ Cout,
                   ushort* __restrict__ vpT,
                   int K, int lda, int ldb, int ldc,
                   long strideA, long strideC, float scale) {
    __shared__ ushort As[2][256 * 64];   // 2 x 32 KB
    __shared__ ushort Bs[2][256 * 64];   // 2 x 32 KB
    int bc, br;
    xcd_swizzle(bc, br);
    int bz = blockIdx.z;
    if (MODE == MODE_LOGITS && bc > br) return;   // fully-masked causal block
    const ushort* Ab = (MODE == MODE_PROJ) ? A + (size_t)(bc >> 2) * strideA
                                           : A + (size_t)bz * strideA;
    const ushort* Bb = (MODE == MODE_PROJ) ? Bt : Bt + (size_t)bz * strideA;
    int brow = br * 256, bcol = bc * 256;
    int t = threadIdx.x, lane = t & 63, wid = t >> 6;
    int wr = wid >> 2, wc = wid & 3;      // 2x4 waves; wave tile 128x64
    int nkt = K / 64;

    // staging sources: gload j covers LDS rows [j*64, j*64+64) linearly;
    // inverse-swizzled global source (rule #21), swizzle byte^=(row&7)<<4
    const ushort* aSrc[4];
    const ushort* bSrc[4];
    int oL[4];
    #pragma unroll
    for (int j = 0; j < 4; ++j) {
        int o = (j * 512 + t) * 16;                 // linear LDS byte offset
        int row = o >> 7;
        int colb = (o & 127) ^ ((row & 7) << 4);
        oL[j] = o >> 1;
        aSrc[j] = Ab + (size_t)(brow + row) * lda + (colb >> 1);
        bSrc[j] = Bb + (size_t)(bcol + row) * ldb + (colb >> 1);
    }
    auto stgA = [&](int tk, int slot, int j0, int j1) {
        ushort* d = &As[slot][0];
        GLOAD(d + oL[j0], aSrc[j0] + tk * 64);
        GLOAD(d + oL[j1], aSrc[j1] + tk * 64);
    };
    auto stgB = [&](int tk, int slot, int j0, int j1) {
        ushort* d = &Bs[slot][0];
        GLOAD(d + oL[j0], bSrc[j0] + tk * 64);
        GLOAD(d + oL[j1], bSrc[j1] + tk * 64);
    };

    // fragment read byte-offsets (ks=0; ks=1 is ^64)
    int rdA[2][4], rdB[4];
    #pragma unroll
    for (int mh = 0; mh < 2; ++mh)
        #pragma unroll
        for (int m = 0; m < 4; ++m) {
            int ra = wr * 128 + mh * 64 + m * 16 + (lane & 15);
            int cb = (lane >> 4) * 16;
            rdA[mh][m] = ra * 128 + (cb ^ ((ra & 7) << 4));
        }
    #pragma unroll
    for (int nf = 0; nf < 4; ++nf) {
        int rb = (nf >> 1) * 128 + wc * 32 + (nf & 1) * 16 + (lane & 15);
        int cb = (lane >> 4) * 16;
        rdB[nf] = rb * 128 + (cb ^ ((rb & 7) << 4));
    }

    f32x4_t acc[8][4];
    #pragma unroll
    for (int m = 0; m < 8; ++m)
        #pragma unroll
        for (int n = 0; n < 4; ++n)
            acc[m][n] = (f32x4_t){0.f, 0.f, 0.f, 0.f};

    bf16x8_t af[4][2], bfr[4][2];

    auto readAh = [&](int slot, int mh) {   // 8 ds_read_b128
        const char* base = (const char*)&As[slot][0];
        #pragma unroll
        for (int m = 0; m < 4; ++m) {
            af[m][0] = *(const bf16x8_t*)(base + rdA[mh][m]);
            af[m][1] = *(const bf16x8_t*)(base + (rdA[mh][m] ^ 64));
        }
    };
    auto readBh = [&](int slot, int nh) {   // 4 ds_read_b128
        const char* base = (const char*)&Bs[slot][0];
        #pragma unroll
        for (int n = 0; n < 2; ++n) {
            int nf = nh * 2 + n;
            bfr[nf][0] = *(const bf16x8_t*)(base + rdB[nf]);
            bfr[nf][1] = *(const bf16x8_t*)(base + (rdB[nf] ^ 64));
        }
    };

#define QUAD(MH, NH)                                                                \
    do { __builtin_amdgcn_s_setprio(1);                                             \
        _Pragma("unroll") for (int m = 0; m < 4; ++m)                               \
        _Pragma("unroll") for (int n = 0; n < 2; ++n)                               \
        _Pragma("unroll") for (int ks = 0; ks < 2; ++ks)                            \
            acc[(MH) * 4 + m][(NH) * 2 + n] = __builtin_amdgcn_mfma_f32_16x16x32_bf16( \
                af[m][ks], bfr[(NH) * 2 + n][ks], acc[(MH) * 4 + m][(NH) * 2 + n], 0, 0, 0); \
        __builtin_amdgcn_s_setprio(0); } while (0)

    // prologue: tile 0 fully, in gate-friendly order: Bh0, Ah0, Bh1, Ah1
    stgB(0, 0, 0, 1); stgA(0, 0, 0, 2); stgB(0, 0, 2, 3); stgA(0, 0, 1, 3);
    GATE(4);                                   // Bh0 + Ah0 landed
    __builtin_amdgcn_s_barrier();

    for (int y = 0; y < nkt; ++y) {
        int cur = y & 1, nxt = cur ^ 1;
        bool st = (y + 1 < nkt);
        // P1 (Q00): reads Ah0,Bh0(cur); stage Bh0'(y+1)
        readAh(cur, 0); readBh(cur, 0);
        if (st) stgB(y + 1, nxt, 0, 1);
        PRE_BAR(); QUAD(0, 0);
        if (st) { GATE(4); } else { GATE(2); }   // Bh1(cur) landed
        POST_BAR();
        // P2 (Q01): reads Bh1(cur); stage Ah0'(y+1)
        readBh(cur, 1);
        if (st) stgA(y + 1, nxt, 0, 2);
        PRE_BAR(); QUAD(0, 1);
        if (st) { GATE(4); } else { GATE(0); }   // Ah1(cur) landed
        POST_BAR();
        // P3 (Q11): reads Ah1(cur); stage Bh1'(y+1)
        readAh(cur, 1);
        if (st) stgB(y + 1, nxt, 2, 3);
        PRE_BAR(); QUAD(1, 1); POST_BAR();
        // P4 (Q10): no reads; stage Ah1'(y+1); gate next tile's P1 halves
        if (st) stgA(y + 1, nxt, 1, 3);
        PRE_BAR(); QUAD(1, 0);
        if (st) { GATE(4); }                     // Bh0',Ah0'(y+1) landed
        POST_BAR();
    }
#undef QUAD

    // epilogue: row = brow + wr*128 + mh*64 + m*16 + (lane>>4)*4 + j
    //           col = bcol + (nf>>1)*128 + wc*32 + (nf&1)*16 + (lane&15)
    int crow0 = brow + wr * 128 + ((lane >> 4) * 4);
    int ccol0 = wc * 32 + (lane & 15);
    if (MODE == MODE_PROJ) {
        #pragma unroll
        for (int mf = 0; mf < 8; ++mf) {
            int rowg = crow0 + (mf >> 2) * 64 + (mf & 3) * 16;
            #pragma unroll
            for (int nf = 0; nf < 4; ++nf) {
                int gcol = bcol + (nf >> 1) * 128 + ccol0 + (nf & 1) * 16;
                float bv = bias[gcol];
                if (bc < 8) {   // q,k -> qkvp [8192][2048]
                    ushort* C = (ushort*)Cout;
                    #pragma unroll
                    for (int j = 0; j < 4; ++j)
                        C[(size_t)(rowg + j) * 2048 + gcol] = f32_to_bf16(acc[mf][nf][j] + bv);
                } else {        // v -> vpT [B][1024][2048]
                    int d = gcol - 2048;
                    int b = rowg >> 11, s = rowg & 2047;
                    ushort4 o;
                    o.x = f32_to_bf16(acc[mf][nf][0] + bv);
                    o.y = f32_to_bf16(acc[mf][nf][1] + bv);
                    o.z = f32_to_bf16(acc[mf][nf][2] + bv);
                    o.w = f32_to_bf16(acc[mf][nf][3] + bv);
                    *(ushort4*)&vpT[(size_t)b * D_DIM * S_LEN + (size_t)d * S_LEN + s] = o;
                }
            }
        }
    } else {
        float* C = (float*)Cout + (size_t)bz * strideC;
        #pragma unroll
        for (int mf = 0; mf < 8; ++mf) {
            int rowg = crow0 + (mf >> 2) * 64 + (mf & 3) * 16;
            #pragma unroll
            for (int nf = 0; nf < 4; ++nf) {
                int col = bcol + (nf >> 1) * 128 + ccol0 + (nf & 1) * 16;
                #pragma unroll
                for (int j = 0; j < 4; ++j)
                    C[(size_t)(rowg + j) * ldc + col] = acc[mf][nf][j] * scale;
            }
        }
    }
}

// =====================================================================
// OUT GEMM (unchanged r6 pipelined kernel): 256x128, BK=64, 3 slots.
// =====================================================================
#define LGKM(N) do { asm volatile("s_waitcnt lgkmcnt(" #N ")" ::: "memory"); \
    __builtin_amdgcn_sched_barrier(0); } while (0)

__global__ __launch_bounds__(512, 2)
void gemm_out_kernel(const ushort* __restrict__ A, const ushort* __restrict__ Bt,
                     void* __restrict__ Cout,
                     int K, int lda, int ldb, int ldc,
                     long strideA, long strideB, long strideC, float scale) {
    __shared__ ushort As[3][256 * 64];
    __shared__ ushort Bs[3][128 * 64];
    int bc, br;
    xcd_swizzle(bc, br);
    int bz = blockIdx.z;
    const ushort* Ab = A + (size_t)bz * strideA;
    const ushort* Bb = Bt + (size_t)bz * strideB;
    int brow = br * 256, bcol = bc * 128;
    int t = threadIdx.x, lane = t & 63, wid = t >> 6;
    int wr = wid >> 1, wc = wid & 1;
    int nkt = min(K / 64, (brow + 256) / 64);

    const ushort* aSrc[4];
    const ushort* bSrc[2];
    int oA[4], oB[2];
    #pragma unroll
    for (int j = 0; j < 4; ++j) {
        int o = (j * 512 + t) * 16;
        int row = o >> 7;
        int col = (o & 127) ^ ((row & 7) << 4);
        oA[j] = o >> 1;
        aSrc[j] = Ab + (size_t)(brow + row) * lda + (col >> 1);
    }
    #pragma unroll
    for (int j = 0; j < 2; ++j) {
        int o = (j * 512 + t) * 16;
        int row = o >> 7;
        int col = (o & 127) ^ ((row & 7) << 4);
        oB[j] = o >> 1;
        bSrc[j] = Bb + (size_t)(bcol + row) * ldb + (col >> 1);
    }
    auto stage = [&](int tk, int slot) {
        ushort* dA = &As[slot][0];
        ushort* dB = &Bs[slot][0];
        #pragma unroll
        for (int j = 0; j < 4; ++j) GLOAD(dA + oA[j], aSrc[j] + tk * 64);
        #pragma unroll
        for (int j = 0; j < 2; ++j) GLOAD(dB + oB[j], bSrc[j] + tk * 64);
    };

    int rdA[4][2], rdB[4][2];
    #pragma unroll
    for (int m = 0; m < 4; ++m) {
        int ra = wr * 64 + m * 16 + (lane & 15);
        #pragma unroll
        for (int ks = 0; ks < 2; ++ks) {
            int cb = ks * 64 + ((lane >> 4) * 16);
            rdA[m][ks] = ra * 128 + (cb ^ ((ra & 7) << 4));
        }
    }
    #pragma unroll
    for (int n = 0; n < 4; ++n) {
        int rb = wc * 64 + n * 16 + (lane & 15);
        #pragma unroll
        for (int ks = 0; ks < 2; ++ks) {
            int cb = ks * 64 + ((lane >> 4) * 16);
            rdB[n][ks] = rb * 128 + (cb ^ ((rb & 7) << 4));
        }
    }

    f32x4_t acc[4][4];
    #pragma unroll
    for (int m = 0; m < 4; ++m)
        #pragma unroll
        for (int n = 0; n < 4; ++n)
            acc[m][n] = (f32x4_t){0.f, 0.f, 0.f, 0.f};

    bf16x8_t aE0[4], aE1[4], bE0[4], bE1[4];
    bf16x8_t aO0[4], aO1[4], bO0[4], bO1[4];

#define MF16(AV, BV)                                                           \
    do { __builtin_amdgcn_s_setprio(1);                                        \
        _Pragma("unroll") for (int m = 0; m < 4; ++m)                          \
        _Pragma("unroll") for (int n = 0; n < 4; ++n)                          \
            acc[m][n] = __builtin_amdgcn_mfma_f32_16x16x32_bf16(               \
                AV[m], BV[n], acc[m][n], 0, 0, 0);                             \
        __builtin_amdgcn_s_setprio(0); } while (0)

#define TILE_BODY(X, CA0, CA1, CB0, CB1, NA0, NA1, NB0, NB1)                   \
    do {                                                                       \
        int x_ = (X);                                                          \
        __builtin_amdgcn_s_barrier();                                          \
        if (x_ + 2 < nkt) stage(x_ + 2, (x_ + 2) % 3);                         \
        if (x_ + 1 < nkt) { if (x_ + 2 < nkt) { GATE(6); } else { GATE(0); } } \
        __builtin_amdgcn_s_barrier();                                          \
        {                                                                      \
            const char* nA = (const char*)&As[(x_ + 1) % 3][0];                \
            const char* nB = (const char*)&Bs[(x_ + 1) % 3][0];                \
            if (x_ + 1 < nkt) {                                                \
                _Pragma("unroll") for (int n = 0; n < 4; ++n)                  \
                    NB0[n] = *(const bf16x8_t*)(nB + rdB[n][0]);               \
                _Pragma("unroll") for (int m = 0; m < 4; ++m)                  \
                    NA0[m] = *(const bf16x8_t*)(nA + rdA[m][0]);               \
                LGKM(8);                                                       \
            } else { LGKM(0); }                                                \
            MF16(CA0, CB0);                                                    \
            if (x_ + 1 < nkt) {                                                \
                _Pragma("unroll") for (int n = 0; n < 4; ++n)                  \
                    NB1[n] = *(const bf16x8_t*)(nB + rdB[n][1]);               \
                _Pragma("unroll") for (int m = 0; m < 4; ++m)                  \
                    NA1[m] = *(const bf16x8_t*)(nA + rdA[m][1]);               \
            }                                                                  \
            MF16(CA1, CB1);                                                    \
        }                                                                      \
    } while (0)

    stage(0, 0);
    stage(1, 1);
    GATE(6);
    __builtin_amdgcn_s_barrier();
    {
        const char* pA = (const char*)&As[0][0];
        const char* pB = (const char*)&Bs[0][0];
        #pragma unroll
        for (int n = 0; n < 4; ++n) bE0[n] = *(const bf16x8_t*)(pB + rdB[n][0]);
        #pragma unroll
        for (int m = 0; m < 4; ++m) aE0[m] = *(const bf16x8_t*)(pA + rdA[m][0]);
        #pragma unroll
        for (int n = 0; n < 4; ++n) bE1[n] = *(const bf16x8_t*)(pB + rdB[n][1]);
        #pragma unroll
        for (int m = 0; m < 4; ++m) aE1[m] = *(const bf16x8_t*)(pA + rdA[m][1]);
    }

    int nhalf = nkt >> 1;
    for (int it = 0; it < nhalf; ++it) {
        int x = 2 * it;
        TILE_BODY(x,     aE0, aE1, bE0, bE1, aO0, aO1, bO0, bO1);
        TILE_BODY(x + 1, aO0, aO1, bO0, bO1, aE0, aE1, bE0, bE1);
    }
#undef TILE_BODY
#undef MF16

    float* C = (float*)Cout + (size_t)bz * strideC;
    int crow0 = brow + wr * 64 + ((lane >> 4) * 4);
    int ccol0 = bcol + wc * 64 + (lane & 15);
    #pragma unroll
    for (int mf = 0; mf < 4; ++mf)
        #pragma unroll
        for (int nf = 0; nf < 4; ++nf) {
            int col = ccol0 + nf * 16;
            #pragma unroll
            for (int j = 0; j < 4; ++j) {
                int rowg = crow0 + mf * 16 + j;
                C[(size_t)rowg * ldc + col] = acc[mf][nf][j] * scale;
            }
        }
}

// ---------------- causal row softmax, skips fully-masked chunks ----------------
__global__ __launch_bounds__(256)
void softmax_causal_kernel(float* __restrict__ attn, ushort* __restrict__ attn_bf) {
    int rowid = blockIdx.x;
    int i = rowid & (S_LEN - 1);
    float* lrow = attn + (size_t)rowid * S_LEN;
    ushort* brw = attn_bf + (size_t)rowid * S_LEN;
    int t = threadIdx.x;
    int nvalid = i + 1;
    int nact = (nvalid + 255) >> 8;     // active 256-wide chunks

    float vals[8];
    float lmax = -1e30f;
    #pragma unroll
    for (int it = 0; it < 8; ++it) {
        if (it < nact) {
            int j = it * 256 + t;
            float v = (j < nvalid) ? lrow[j] : -1e30f;
            vals[it] = v;
            lmax = fmaxf(lmax, v);
        }
    }
    #pragma unroll
    for (int off = 32; off > 0; off >>= 1)
        lmax = fmaxf(lmax, __shfl_xor(lmax, off));

    __shared__ float redm[4];
    __shared__ float reds[4];
    int wave = t >> 6, lane = t & 63;
    if (lane == 0) redm[wave] = lmax;
    __syncthreads();
    float m = fmaxf(fmaxf(redm[0], redm[1]), fmaxf(redm[2], redm[3]));

    float lsum = 0.f;
    #pragma unroll
    for (int it = 0; it < 8; ++it) {
        if (it < nact) {
            int j = it * 256 + t;
            float e = (j < nvalid) ? __expf(vals[it] - m) : 0.f;
            vals[it] = e;
            lsum += e;
        }
    }
    #pragma unroll
    for (int off = 32; off > 0; off >>= 1)
        lsum += __shfl_xor(lsum, off);
    if (lane == 0) reds[wave] = lsum;
    __syncthreads();
    float denom = reds[0] + reds[1] + reds[2] + reds[3];
    float inv = 1.f / denom;

    #pragma unroll
    for (int it = 0; it < 8; ++it) {
        int j = it * 256 + t;
        if (it < nact) {
            float p = vals[it] * inv;
            lrow[j] = p;
            brw[j] = f32_to_bf16(p);
        } else {
            lrow[j] = 0.f;
            brw[j] = 0;
        }
    }
}

extern "C" void kernel_launch(void* const* d_in, const int* in_sizes, int n_in,
                              void* d_out, int out_size, void* d_ws, size_t ws_size,
                              hipStream_t stream) {
    const float* v  = (const float*)d_in[0];
    const float* k  = (const float*)d_in[1];
    const float* q  = (const float*)d_in[2];
    // d_in[3] = mask, unused (causality applied by index)
    const float* Wq = (const float*)d_in[4];
    const float* bq = (const float*)d_in[5];
    const float* Wk = (const float*)d_in[6];
    const float* bk = (const float*)d_in[7];
    const float* Wv = (const float*)d_in[8];
    const float* bv = (const float*)d_in[9];

    float* out  = (float*)d_out;                                        // [B,S,D]
    float* attn = (float*)d_out + (size_t)BATCH * S_LEN * D_DIM;        // [B,S,S]

    char* ws = (char*)d_ws;
    const size_t NTOK = (size_t)BATCH * S_LEN;                // 8192
    ushort* xqkv  = (ushort*)(ws);                            // [3][8192][1024] bf16, 48 MiB
    ushort* qkvp  = (ushort*)(ws + 48u * 1024 * 1024);        // [8192][2048] bf16 (q|k), 32 MiB
    ushort* vpT   = (ushort*)(ws + 80u * 1024 * 1024);        // [B][1024][2048] bf16, 16 MiB
    ushort* WT    = (ushort*)(ws + 96u * 1024 * 1024);        // [3072][1024] bf16, 6 MiB
    float*  bias3 = (float*)(ws + 102u * 1024 * 1024);        // 3072 f32
    ushort* attn_bf = (ushort*)(ws);                          // alias over xqkv (dead after proj)

    const int n4 = (int)(NTOK * D_DIM / 4);
    cvt3_kernel<<<dim3(1024, 3), dim3(256), 0, stream>>>(q, k, v, xqkv, n4);

    transpose_cvt_kernel<<<dim3(16, 16), dim3(256), 0, stream>>>(Wq, WT, D_DIM, D_DIM);
    transpose_cvt_kernel<<<dim3(16, 16), dim3(256), 0, stream>>>(Wk, WT + (size_t)D_DIM * D_DIM, D_DIM, D_DIM);
    transpose_cvt_kernel<<<dim3(16, 16), dim3(256), 0, stream>>>(Wv, WT + 2 * (size_t)D_DIM * D_DIM, D_DIM, D_DIM);
    bias_concat_kernel<<<dim3(12), dim3(256), 0, stream>>>(bq, bk, bv, bias3);

    // merged projections: M=8192, N=3072 (q|k cols -> qkvp, v cols -> vpT)
    gemm_q_kernel<MODE_PROJ><<<dim3(12, 32, 1), dim3(512), 0, stream>>>(
        xqkv, WT, bias3, qkvp, vpT, D_DIM, D_DIM, D_DIM, 2048,
        (long)NTOK * D_DIM, 0, 1.f);

    // logits = qp @ kp^T / 32, causal blocks only, fp32 into attn region of d_out
    gemm_q_kernel<MODE_LOGITS><<<dim3(8, 8, BATCH), dim3(512), 0, stream>>>(
        qkvp, qkvp + D_DIM, nullptr, attn, nullptr, D_DIM, 2048, 2048, S_LEN,
        (long)S_LEN * 2048, (long)S_LEN * S_LEN, 0.03125f);

    // softmax rows (fp32 in-place in d_out; bf16 copy for PV)
    softmax_causal_kernel<<<dim3((int)NTOK), dim3(256), 0, stream>>>(attn, attn_bf);

    // out = attn_bf @ vp (via vpT), causal K-limit
    gemm_out_kernel<<<dim3(8, 8, BATCH), dim3(512), 0, stream>>>(
        attn_bf, vpT, out, S_LEN, S_LEN, S_LEN, D_DIM,
        (long)S_LEN * S_LEN, (long)D_DIM * S_LEN, (long)S_LEN * D_DIM, 1.f);
}